// Round 6
// baseline (675.528 us; speedup 1.0000x reference)
//
#include <hip/hip_runtime.h>
#include <hip/hip_bf16.h>
#include <stdint.h>

// Sizes (fixed by the problem)
#define NN 512
#define DD 128
#define EE 16384

typedef short bf16x8 __attribute__((ext_vector_type(8)));
typedef short bf16x4 __attribute__((ext_vector_type(4)));
typedef float f32x4  __attribute__((ext_vector_type(4)));
typedef unsigned int u32;

__device__ __forceinline__ short f2bf(float f) {
    union { __hip_bfloat16 h; short s; } u;
    u.h = __float2bfloat16(f);
    return u.s;
}
__device__ __forceinline__ u32 pk2(float a, float b) {
    return (u32)(unsigned short)f2bf(a) | ((u32)(unsigned short)f2bf(b) << 16);
}

// async global->LDS 16B copy. LDS dest = wave-uniform base + lane*16 (linear in
// tid); XOR swizzle is applied on the SOURCE chunk index.
typedef __attribute__((address_space(3))) unsigned int lds_u32;
typedef __attribute__((address_space(1))) const unsigned int glb_u32;
__device__ __forceinline__ void gll16(void* l, const void* g) {
    __builtin_amdgcn_global_load_lds((glb_u32*)g, (lds_u32*)l, 16, 0, 0);
}

// ---------------- tiny prep kernels ----------------

__global__ void k_zero(float* __restrict__ At) {
    At[blockIdx.x * 256 + threadIdx.x] = 0.0f;
}

// Build At[dst][src] += 1.  Robust to int32 or int64 input (for int64 LE every
// odd 32-bit word is 0 since values < 512).
__global__ void k_edges(const int* __restrict__ ei, float* __restrict__ At) {
    __shared__ int flag;
    if (threadIdx.x == 0) flag = 0;
    __syncthreads();
    int any = 0;
    for (int i = threadIdx.x; i < EE; i += blockDim.x) any |= ei[2 * i + 1];
    if (any) atomicOr(&flag, 1);
    __syncthreads();
    const bool is32 = (flag != 0);
    for (int e = threadIdx.x; e < EE; e += blockDim.x) {
        int src, dst;
        if (is32) { src = ei[e];     dst = ei[EE + e]; }
        else      { src = ei[2 * e]; dst = ei[2 * (EE + e)]; }
        atomicAdd(&At[dst * NN + src], 1.0f);
    }
}

// Wt2[s][n][d] = bf16(W[(s*128+d)*128 + n])  (k_y W staging)
__global__ void k_wt2(const float* __restrict__ W, short* __restrict__ Wt2) {
    int t = blockIdx.x * 256 + threadIdx.x;     // t = kk*128 + n, kk = s*128+d
    int kk = t >> 7, n = t & 127;
    int s = kk >> 7, d = kk & 127;
    Wt2[s * 16384 + n * 128 + d] = f2bf(W[t]);
}

// Pack At into MFMA A-fragment tile order: tile T = rt*16 + kt covers rows
// rt*16..+16, cols kt*32..+32; lane l holds At[rt*16 + (l&15)][kt*32 + (l>>4)*8 + e].
__global__ void k_pack_at(const float* __restrict__ At, short* __restrict__ Atp) {
    int t = blockIdx.x * 256 + threadIdx.x;     // 32768 threads
    int T = t >> 6, l = t & 63;
    int row = (T >> 4) * 16 + (l & 15);
    int col = (T & 15) * 32 + (l >> 4) * 8;
    const float* s = &At[row * 512 + col];
    bf16x8 p;
    #pragma unroll
    for (int e = 0; e < 8; ++e) p[e] = f2bf(s[e]);
    *(bf16x8*)&Atp[(size_t)T * 512 + l * 8] = p;
}

// Pack W0 into MFMA B-fragment tiles: T = nt*4 + kt; lane l holds
// W0^T[n = nt*16+(l&15)][d = kt*32+(l>>4)*8+e] = W[d*128+n].  32 KB, L2-hot.
__global__ void k_pack_w0(const float* __restrict__ W, short* __restrict__ W0p) {
    int t = blockIdx.x * 256 + threadIdx.x;     // 2048 threads
    int T = t >> 6, l = t & 63;
    int nt = T >> 2, kt = T & 3;
    int n  = nt * 16 + (l & 15);
    int d0 = kt * 32 + (l >> 4) * 8;
    bf16x8 p;
    #pragma unroll
    for (int e = 0; e < 8; ++e) p[e] = f2bf(W[(d0 + e) * 128 + n]);
    *(bf16x8*)&W0p[(size_t)T * 512 + l * 8] = p;
}

// ---------------- k_y: Y1T / Y2 from one pass over X (round-0, proven) --------
// block b: i = b>>2, j0 = (b&3)*128; rows m = (i, j0+r).
// Y1T[i][n][m] = bf16( sum_d X[i][m][d] W1[d][n] )  -> flat B^T[(i,n)][m]
// Y2 [i][m][n] = bf16( sum_d X[i][m][d] W2[d][n] )  (natural)
__global__ __launch_bounds__(256) void k_y(const float* __restrict__ X,
                                           const short* __restrict__ Wt2,
                                           short* __restrict__ Y1T,
                                           short* __restrict__ Y2) {
    __shared__ __align__(16) short Xs[16384];   // [kb][r][64 swizzled]
    __shared__ __align__(16) short Ws[16384];   // [kb][n][64 swizzled]; epilogue scratch

    const int tid  = threadIdx.x;
    const int lane = tid & 63;
    const int wv   = tid >> 6;
    const int wr   = (wv >> 1) * 64;
    const int wc   = (wv & 1) * 64;
    const int lm   = lane & 15;
    const int lq   = lane >> 4;
    const int i  = blockIdx.x >> 2;
    const int j0 = (blockIdx.x & 3) * 128;

    // stage X tile once: fp32 -> bf16, contiguous 64 KB region, coalesced
    #pragma unroll
    for (int it = 0; it < 16; ++it) {
        int g = tid + it * 256;
        int r = g >> 5, c4 = g & 31;
        float4 v = *(const float4*)&X[i * 65536 + (j0 + r) * 128 + c4 * 4];
        int kb = c4 >> 4, c = c4 & 15, p = c >> 1, h2 = c & 1;
        bf16x4 pc; pc[0] = f2bf(v.x); pc[1] = f2bf(v.y); pc[2] = f2bf(v.z); pc[3] = f2bf(v.w);
        *(bf16x4*)&Xs[kb * 8192 + r * 64 + ((p ^ (r & 7)) * 8 + h2 * 4)] = pc;
    }

    #pragma unroll
    for (int s = 1; s <= 2; ++s) {
        // stage W[s] (both kb halves): dest linear, src chunk XOR-swizzled
        #pragma unroll
        for (int it = 0; it < 8; ++it) {
            int slot = it * 256 + tid;              // = kb*1024 + n*8 + pc
            int kb = slot >> 10, rem = slot & 1023;
            int n = rem >> 3, pc = rem & 7;
            gll16(&Ws[slot * 8],
                  &Wt2[s * 16384 + n * 128 + kb * 64 + ((pc ^ (n & 7)) * 8)]);
        }
        __syncthreads();

        f32x4 acc[4][4] = {};
        #pragma unroll
        for (int kb = 0; kb < 2; ++kb)
            #pragma unroll
            for (int ks = 0; ks < 2; ++ks) {
                bf16x8 af[4], bf[4];
                #pragma unroll
                for (int mf = 0; mf < 4; ++mf) {
                    int R = wr + mf * 16 + lm, Cc = ks * 4 + lq;
                    af[mf] = *(const bf16x8*)&Xs[kb * 8192 + R * 64 + (Cc ^ (R & 7)) * 8];
                }
                #pragma unroll
                for (int nf = 0; nf < 4; ++nf) {
                    int R = wc + nf * 16 + lm, Cc = ks * 4 + lq;
                    bf[nf] = *(const bf16x8*)&Ws[kb * 8192 + R * 64 + (Cc ^ (R & 7)) * 8];
                }
                #pragma unroll
                for (int mf = 0; mf < 4; ++mf)
                    #pragma unroll
                    for (int nf = 0; nf < 4; ++nf)
                        acc[mf][nf] = __builtin_amdgcn_mfma_f32_16x16x32_bf16(
                            af[mf], bf[nf], acc[mf][nf], 0, 0, 0);
            }
        __syncthreads();   // MFMA reads of Ws done -> safe to reuse as scratch

        if (s == 1) {
            // transposed epilogue: T[n][m] u32-pairs, XOR-swizzled, b64 writes
            u32* T = (u32*)Ws;
            #pragma unroll
            for (int mf = 0; mf < 4; ++mf)
                #pragma unroll
                for (int nf = 0; nf < 4; ++nf) {
                    int n = wc + nf * 16 + lm;
                    int jb = wr + mf * 16 + lq * 4;   // multiple of 4
                    int w = jb >> 1;                   // even
                    u32 lo = pk2(acc[mf][nf][0], acc[mf][nf][1]);
                    u32 hi = pk2(acc[mf][nf][2], acc[mf][nf][3]);
                    uint2 val; val.x = lo; val.y = hi;
                    *(uint2*)&T[n * 64 + (w ^ (n & 28))] = val;
                }
            __syncthreads();
            #pragma unroll
            for (int it = 0; it < 8; ++it) {
                int ch = tid & 15, n = (tid >> 4) + it * 16;
                uint4 q = *(const uint4*)&T[n * 64 + ((ch * 4) ^ (n & 28))];
                *(uint4*)&Y1T[i * 65536 + n * 512 + j0 + ch * 8] = q;
            }
            __syncthreads();   // before s=2 W staging overwrites T
        } else {
            // natural epilogue via LDS round-trip -> coalesced 16B stores
            #pragma unroll
            for (int mf = 0; mf < 4; ++mf)
                #pragma unroll
                for (int nf = 0; nf < 4; ++nf)
                    #pragma unroll
                    for (int r = 0; r < 4; ++r)
                        Ws[(wr + mf * 16 + lq * 4 + r) * 128 + wc + nf * 16 + lm]
                            = f2bf(acc[mf][nf][r]);
            __syncthreads();
            #pragma unroll
            for (int it = 0; it < 8; ++it) {
                int q = tid + it * 256;
                int row = q >> 4, oc = (q & 15) * 8;
                *(bf16x8*)&Y2[i * 65536 + (j0 + row) * 128 + oc]
                    = *(const bf16x8*)&Ws[row * 128 + oc];
            }
        }
    }
}

// ---------------- k_t: bf16 transpose Y2[k][j][n] -> Y2T[j][n][k] ----------------
__global__ __launch_bounds__(256) void k_t(const short* __restrict__ Y2,
                                           short* __restrict__ Y2T) {
    __shared__ __align__(16) u32 U[128 * 64];   // U[n][a]: (k=2a, 2a+1) packed
    const int tid = threadIdx.x;
    const int bid = (blockIdx.x & 7) * 256 + (blockIdx.x >> 3);   // 2048 % 8 == 0
    const int j  = bid >> 2;
    const int k0 = (bid & 3) * 128;

    const int c8 = tid & 15;         // 8-n chunk
    const int a0 = tid >> 4;         // pair index base
    #pragma unroll
    for (int it = 0; it < 4; ++it) {
        int a = a0 + it * 16;        // 0..63
        const short* r0 = &Y2[(size_t)(k0 + 2 * a) * 65536 + j * 128 + c8 * 8];
        bf16x8 A0 = *(const bf16x8*)r0;
        bf16x8 A1 = *(const bf16x8*)(r0 + 65536);
        #pragma unroll
        for (int cc = 0; cc < 8; ++cc) {
            int n = c8 * 8 + cc;
            U[n * 64 + (a ^ (n & 28))] =
                (u32)(unsigned short)A0[cc] | ((u32)(unsigned short)A1[cc] << 16);
        }
    }
    __syncthreads();
    const int ch = tid & 15;
    const int n0 = tid >> 4;
    #pragma unroll
    for (int it = 0; it < 8; ++it) {
        int n = n0 + it * 16;
        uint4 q = *(const uint4*)&U[n * 64 + ((ch * 4) ^ (n & 28))];
        *(uint4*)&Y2T[j * 65536 + n * 512 + k0 + ch * 8] = q;
    }
}

// ---------------- k_p1: flat GEMM P1x[j][(i,n)] = At @ Y1T^T ----------------
// Y1T is already flat B^T[(i*128+n)][m].  Tile 128(j) x 256(N), 512 thr,
// 8 waves 2x4, 64 KB LDS dbuf, Atp-direct hoisted A-frags, XCD swizzle.
__global__ __launch_bounds__(512, 4) void k_p1(const short* __restrict__ Atp,
                                               const short* __restrict__ Y1T,
                                               short* __restrict__ P1x) {
    __shared__ __align__(16) short sm[32768];   // 64 KB: two 32 KB buffers

    const int tid  = threadIdx.x;
    const int lane = tid & 63;
    const int wv   = tid >> 6;
    const int wrM  = (wv >> 2) * 64;     // j within tile
    const int wcN  = (wv & 3) * 64;      // N within tile
    const int lm   = lane & 15;
    const int lq   = lane >> 4;
    const int lin = (blockIdx.x & 7) * 128 + (blockIdx.x >> 3);   // 1024 % 8 == 0
    const int j0 = (lin & 3) * 128;
    const int N0 = (lin >> 2) * 256;
    const int jt0 = (j0 >> 4) + (wrM >> 4);

    f32x4 acc[4][4] = {};

    // prologue: stage kb=0 into buffer 0 (32 KB: 256 N-rows x 64 k)
    #pragma unroll
    for (int it = 0; it < 4; ++it) {
        int slot = it * 512 + tid;
        int r = slot >> 3, p = slot & 7;
        gll16(&sm[slot * 8], &Y1T[(size_t)(N0 + r) * 512 + ((p ^ (r & 7)) * 8)]);
    }
    __syncthreads();

    for (int kb = 0; kb < 8; ++kb) {
        short* cur = (kb & 1) ? sm + 16384 : sm;
        short* nxt = (kb & 1) ? sm : sm + 16384;

        // A-frags FIRST (oldest vmcnt entries)
        bf16x8 afr[2][4];
        #pragma unroll
        for (int ks = 0; ks < 2; ++ks)
            #pragma unroll
            for (int mf = 0; mf < 4; ++mf)
                afr[ks][mf] = *(const bf16x8*)&Atp[(size_t)((jt0 + mf) * 16 + kb * 2 + ks) * 512 + lane * 8];
        __builtin_amdgcn_sched_barrier(0);

        if (kb < 7) {
            const int k0n = (kb + 1) * 64;
            #pragma unroll
            for (int it = 0; it < 4; ++it) {
                int slot = it * 512 + tid;
                int r = slot >> 3, p = slot & 7;
                gll16(&nxt[slot * 8], &Y1T[(size_t)(N0 + r) * 512 + k0n + ((p ^ (r & 7)) * 8)]);
            }
        }

        #pragma unroll
        for (int ks = 0; ks < 2; ++ks) {
            bf16x8 bf[4];
            #pragma unroll
            for (int nf = 0; nf < 4; ++nf) {
                int R = wcN + nf * 16 + lm, Cc = ks * 4 + lq;
                bf[nf] = *(const bf16x8*)&cur[R * 64 + (Cc ^ (R & 7)) * 8];
            }
            #pragma unroll
            for (int mf = 0; mf < 4; ++mf)
                #pragma unroll
                for (int nf = 0; nf < 4; ++nf)
                    acc[mf][nf] = __builtin_amdgcn_mfma_f32_16x16x32_bf16(
                        afr[ks][mf], bf[nf], acc[mf][nf], 0, 0, 0);
        }
        __syncthreads();
    }

    // epilogue: 128 j-rows x 256 N bf16 via full-LDS roundtrip
    #pragma unroll
    for (int mf = 0; mf < 4; ++mf)
        #pragma unroll
        for (int nf = 0; nf < 4; ++nf)
            #pragma unroll
            for (int rr = 0; rr < 4; ++rr)
                sm[(wrM + mf * 16 + lq * 4 + rr) * 256 + wcN + nf * 16 + lm]
                    = f2bf(acc[mf][nf][rr]);
    __syncthreads();
    #pragma unroll
    for (int it = 0; it < 8; ++it) {
        int q = tid + it * 512;
        int row = q >> 5, oc = (q & 31) * 8;
        *(bf16x8*)&P1x[(size_t)(j0 + row) * 65536 + N0 + oc]
            = *(const bf16x8*)&sm[row * 256 + oc];
    }
}

// ---------------- k_f: out[i][(j,n)] = At@Y2T^T + X@W0 + P1x + b ----------------
// Y2T is flat B^T[(j*128+n)][k]; out is naturally N-flat. Tile 128(i) x 256(N).
__global__ __launch_bounds__(512, 4) void k_f(const float* __restrict__ X,
                                              const short* __restrict__ Atp,
                                              const short* __restrict__ Y2T,
                                              const short* __restrict__ W0p,
                                              const short* __restrict__ P1x,
                                              const float* __restrict__ bias,
                                              float* __restrict__ out) {
    __shared__ __align__(16) short sm[32768];   // 64 KB

    const int tid  = threadIdx.x;
    const int lane = tid & 63;
    const int wv   = tid >> 6;
    const int wrM  = (wv >> 2) * 64;     // i within tile
    const int wcN  = (wv & 3) * 64;      // N within tile
    const int lm   = lane & 15;
    const int lq   = lane >> 4;
    const int lin = (blockIdx.x & 7) * 128 + (blockIdx.x >> 3);
    const int i0  = (lin & 3) * 128;
    const int N0  = (lin >> 2) * 256;
    const int jb0 = N0 >> 7;             // base j of the pair

    f32x4 acc[4][4] = {};

    // ---- phase 1: X@W0 over the j-pair; A = X[i0..+128][jb0..jb0+1][d] ----
    // stage 128 rows x 256 floats (1 KB contiguous per row) -> bf16 swizzled
    #pragma unroll
    for (int it = 0; it < 16; ++it) {
        int g = tid + it * 512;
        int r = g >> 6, c4 = g & 63;
        float4 v = *(const float4*)&X[(size_t)(i0 + r) * 65536 + jb0 * 128 + c4 * 4];
        int jp = c4 >> 5, cc = c4 & 31;
        int kb = cc >> 4, c = cc & 15, p = c >> 1, h2 = c & 1;
        bf16x4 pc; pc[0] = f2bf(v.x); pc[1] = f2bf(v.y); pc[2] = f2bf(v.z); pc[3] = f2bf(v.w);
        *(bf16x4*)&sm[jp * 16384 + kb * 8192 + r * 64 + ((p ^ (r & 7)) * 8 + h2 * 4)] = pc;
    }
    __syncthreads();
    {
        const int jpw = (wv & 3) >> 1;          // wave's j' within pair
        const int ntb = (wv & 1) * 4;           // W0p n-tile base
        #pragma unroll
        for (int kb = 0; kb < 2; ++kb)
            #pragma unroll
            for (int ks = 0; ks < 2; ++ks) {
                int kt = kb * 2 + ks, Cc = ks * 4 + lq;
                bf16x8 af[4], bf[4];
                #pragma unroll
                for (int mf = 0; mf < 4; ++mf) {
                    int R = wrM + mf * 16 + lm;
                    af[mf] = *(const bf16x8*)&sm[jpw * 16384 + kb * 8192 + R * 64 + ((Cc ^ (R & 7)) * 8)];
                }
                #pragma unroll
                for (int nf = 0; nf < 4; ++nf)
                    bf[nf] = *(const bf16x8*)&W0p[(size_t)((ntb + nf) * 4 + kt) * 512 + lane * 8];
                #pragma unroll
                for (int mf = 0; mf < 4; ++mf)
                    #pragma unroll
                    for (int nf = 0; nf < 4; ++nf)
                        acc[mf][nf] = __builtin_amdgcn_mfma_f32_16x16x32_bf16(
                            af[mf], bf[nf], acc[mf][nf], 0, 0, 0);
            }
    }
    __syncthreads();

    // ---- phase 2: At@Y2T^T, K=512, dbuf + hoisted Atp A-frags ----
    const int it0 = (i0 >> 4) + (wrM >> 4);
    #pragma unroll
    for (int it = 0; it < 4; ++it) {
        int slot = it * 512 + tid;
        int r = slot >> 3, p = slot & 7;
        gll16(&sm[slot * 8], &Y2T[(size_t)(N0 + r) * 512 + ((p ^ (r & 7)) * 8)]);
    }
    __syncthreads();

    for (int kb = 0; kb < 8; ++kb) {
        short* cur = (kb & 1) ? sm + 16384 : sm;
        short* nxt = (kb & 1) ? sm : sm + 16384;

        bf16x8 afr[2][4];
        #pragma unroll
        for (int ks = 0; ks < 2; ++ks)
            #pragma unroll
            for (int mf = 0; mf < 4; ++mf)
                afr[ks][mf] = *(const bf16x8*)&Atp[(size_t)((it0 + mf) * 16 + kb * 2 + ks) * 512 + lane * 8];
        __builtin_amdgcn_sched_barrier(0);

        if (kb < 7) {
            const int k0n = (kb + 1) * 64;
            #pragma unroll
            for (int it = 0; it < 4; ++it) {
                int slot = it * 512 + tid;
                int r = slot >> 3, p = slot & 7;
                gll16(&nxt[slot * 8], &Y2T[(size_t)(N0 + r) * 512 + k0n + ((p ^ (r & 7)) * 8)]);
            }
        }

        #pragma unroll
        for (int ks = 0; ks < 2; ++ks) {
            bf16x8 bf[4];
            #pragma unroll
            for (int nf = 0; nf < 4; ++nf) {
                int R = wcN + nf * 16 + lm, Cc = ks * 4 + lq;
                bf[nf] = *(const bf16x8*)&cur[R * 64 + (Cc ^ (R & 7)) * 8];
            }
            #pragma unroll
            for (int mf = 0; mf < 4; ++mf)
                #pragma unroll
                for (int nf = 0; nf < 4; ++nf)
                    acc[mf][nf] = __builtin_amdgcn_mfma_f32_16x16x32_bf16(
                        afr[ks][mf], bf[nf], acc[mf][nf], 0, 0, 0);
        }
        __syncthreads();
    }

    // ---- fused epilogue: + P1x + bias -> fp32 out (N-flat contiguous) ----
    #pragma unroll
    for (int mf = 0; mf < 4; ++mf)
        #pragma unroll
        for (int nf = 0; nf < 4; ++nf)
            #pragma unroll
            for (int rr = 0; rr < 4; ++rr)
                sm[(wrM + mf * 16 + lq * 4 + rr) * 256 + wcN + nf * 16 + lm]
                    = f2bf(acc[mf][nf][rr]);
    __syncthreads();
    #pragma unroll
    for (int it = 0; it < 8; ++it) {
        int q = tid + it * 512;
        int row = q >> 5, oc = (q & 31) * 8;
        int jp2 = oc >> 7, n = oc & 127;
        bf16x8 vs = *(const bf16x8*)&sm[row * 256 + oc];
        bf16x8 vpl = *(const bf16x8*)&P1x[(size_t)(jb0 + jp2) * 65536 + (i0 + row) * 128 + n];
        float4 b0 = *(const float4*)&bias[n];
        float4 b1 = *(const float4*)&bias[n + 4];
        union { short s; __hip_bfloat16 h; } cs, cp;
        float o[8];
        #pragma unroll
        for (int e = 0; e < 8; ++e) {
            cs.s = vs[e]; cp.s = vpl[e];
            o[e] = __bfloat162float(cs.h) + __bfloat162float(cp.h);
        }
        o[0] += b0.x; o[1] += b0.y; o[2] += b0.z; o[3] += b0.w;
        o[4] += b1.x; o[5] += b1.y; o[6] += b1.z; o[7] += b1.w;
        float* op = &out[(size_t)(i0 + row) * 65536 + N0 + oc];
        float4 w0; w0.x = o[0]; w0.y = o[1]; w0.z = o[2]; w0.w = o[3];
        float4 w1; w1.x = o[4]; w1.y = o[5]; w1.z = o[6]; w1.w = o[7];
        *(float4*)op = w0;
        *(float4*)(op + 4) = w1;
    }
}

// ================= fallback path (round-1, proven, 130 MiB ws) =================

__global__ __launch_bounds__(256) void k_agg_fb(const float* __restrict__ X,
                                                const float* __restrict__ At,
                                                short* __restrict__ X1b,
                                                short* __restrict__ X2b) {
    __shared__ short As[128 * 72];
    __shared__ short Bs[128 * 72];
    const int tid  = threadIdx.x;
    const int lane = tid & 63;
    const int wv   = tid >> 6;
    const int wr   = (wv >> 1) * 64;
    const int wc   = (wv & 1) * 64;
    const int lm   = lane & 15;
    const int lq   = lane >> 4;
    int a0, Bbase, Bks, Cbase, Crs;
    short* Cp;
    const int bidx = blockIdx.x;
    if (bidx < 2048) {
        int i = bidx >> 2, jt = bidx & 3;
        a0 = jt * 128; Bbase = i * 65536; Bks = 128;
        Cbase = i * 65536 + jt * 16384; Crs = 128; Cp = X1b;
    } else {
        int bb = bidx - 2048;
        int j = bb >> 2, it = bb & 3;
        a0 = it * 128; Bbase = j * 128; Bks = 65536;
        Cbase = it * 8388608 + j * 128; Crs = 65536; Cp = X2b;
    }
    f32x4 acc[4][4] = {};
    const int d  = tid & 127;
    const int kh = tid >> 7;
    for (int kb = 0; kb < 8; ++kb) {
        const int k0 = kb * 64;
        #pragma unroll
        for (int it8 = 0; it8 < 8; ++it8) {
            int g = tid + it8 * 256;
            int r = g >> 4, kq = (g & 15) * 4;
            float4 v = *(const float4*)&At[(a0 + r) * 512 + k0 + kq];
            bf16x4 p; p[0] = f2bf(v.x); p[1] = f2bf(v.y); p[2] = f2bf(v.z); p[3] = f2bf(v.w);
            *(bf16x4*)&As[r * 72 + kq] = p;
        }
        #pragma unroll
        for (int gi = 0; gi < 4; ++gi) {
            int kg = kh * 4 + gi;
            bf16x8 p;
            #pragma unroll
            for (int jj = 0; jj < 8; ++jj)
                p[jj] = f2bf(X[Bbase + (k0 + kg * 8 + jj) * Bks + d]);
            *(bf16x8*)&Bs[d * 72 + kg * 8] = p;
        }
        __syncthreads();
        #pragma unroll
        for (int ks = 0; ks < 2; ++ks) {
            bf16x8 af[4], bfr[4];
            #pragma unroll
            for (int mf = 0; mf < 4; ++mf)
                af[mf] = *(const bf16x8*)&As[(wr + mf * 16 + lm) * 72 + ks * 32 + lq * 8];
            #pragma unroll
            for (int nf = 0; nf < 4; ++nf)
                bfr[nf] = *(const bf16x8*)&Bs[(wc + nf * 16 + lm) * 72 + ks * 32 + lq * 8];
            #pragma unroll
            for (int mf = 0; mf < 4; ++mf)
                #pragma unroll
                for (int nf = 0; nf < 4; ++nf)
                    acc[mf][nf] = __builtin_amdgcn_mfma_f32_16x16x32_bf16(
                        af[mf], bfr[nf], acc[mf][nf], 0, 0, 0);
        }
        __syncthreads();
    }
    #pragma unroll
    for (int mf = 0; mf < 4; ++mf)
        #pragma unroll
        for (int nf = 0; nf < 4; ++nf)
            #pragma unroll
            for (int r = 0; r < 4; ++r) {
                int row = wr + mf * 16 + lq * 4 + r;
                int col = wc + nf * 16 + lm;
                Cp[Cbase + row * Crs + col] = f2bf(acc[mf][nf][r]);
            }
}

__global__ __launch_bounds__(256) void k_final_fb(const float* __restrict__ X,
                                                  const short* __restrict__ X1b,
                                                  const short* __restrict__ X2b,
                                                  const short* __restrict__ Wt2,
                                                  const float* __restrict__ bias,
                                                  float* __restrict__ out) {
    __shared__ short As[128 * 72];
    __shared__ short Ws[128 * 72];
    const int tid  = threadIdx.x;
    const int lane = tid & 63;
    const int wv   = tid >> 6;
    const int wr   = (wv >> 1) * 64;
    const int wc   = (wv & 1) * 64;
    const int lm   = lane & 15;
    const int lq   = lane >> 4;
    const int m0   = blockIdx.x * 128;
    f32x4 acc[4][4] = {};
    for (int ph = 0; ph < 6; ++ph) {
        const int s = ph >> 1, h = ph & 1;
        if (s == 0) {
            #pragma unroll
            for (int it8 = 0; it8 < 8; ++it8) {
                int g = tid + it8 * 256;
                int r = g >> 4, kq = (g & 15) * 4;
                float4 v = *(const float4*)&X[(m0 + r) * 128 + h * 64 + kq];
                bf16x4 p; p[0] = f2bf(v.x); p[1] = f2bf(v.y); p[2] = f2bf(v.z); p[3] = f2bf(v.w);
                *(bf16x4*)&As[r * 72 + kq] = p;
            }
        } else {
            const short* src = (s == 1) ? X1b : X2b;
            #pragma unroll
            for (int it4 = 0; it4 < 4; ++it4) {
                int g = tid + it4 * 256;
                int r = g >> 3, ko = (g & 7) * 8;
                *(bf16x8*)&As[r * 72 + ko] =
                    *(const bf16x8*)&src[(m0 + r) * 128 + h * 64 + ko];
            }
        }
        #pragma unroll
        for (int it4 = 0; it4 < 4; ++it4) {
            int g = tid + it4 * 256;
            int n = g >> 3, ko = (g & 7) * 8;
            *(bf16x8*)&Ws[n * 72 + ko] =
                *(const bf16x8*)&Wt2[s * 16384 + n * 128 + h * 64 + ko];
        }
        __syncthreads();
        #pragma unroll
        for (int ks = 0; ks < 2; ++ks) {
            bf16x8 af[4], bfr[4];
            #pragma unroll
            for (int mf = 0; mf < 4; ++mf)
                af[mf] = *(const bf16x8*)&As[(wr + mf * 16 + lm) * 72 + ks * 32 + lq * 8];
            #pragma unroll
            for (int nf = 0; nf < 4; ++nf)
                bfr[nf] = *(const bf16x8*)&Ws[(wc + nf * 16 + lm) * 72 + ks * 32 + lq * 8];
            #pragma unroll
            for (int mf = 0; mf < 4; ++mf)
                #pragma unroll
                for (int nf = 0; nf < 4; ++nf)
                    acc[mf][nf] = __builtin_amdgcn_mfma_f32_16x16x32_bf16(
                        af[mf], bfr[nf], acc[mf][nf], 0, 0, 0);
        }
        __syncthreads();
    }
    #pragma unroll
    for (int nf = 0; nf < 4; ++nf) {
        float bv = bias[wc + nf * 16 + lm];
        #pragma unroll
        for (int mf = 0; mf < 4; ++mf)
            #pragma unroll
            for (int r = 0; r < 4; ++r) {
                int row = m0 + wr + mf * 16 + lq * 4 + r;
                int col = wc + nf * 16 + lm;
                out[row * 128 + col] = acc[mf][nf][r] + bv;
            }
    }
}

extern "C" void kernel_launch(void* const* d_in, const int* in_sizes, int n_in,
                              void* d_out, int out_size, void* d_ws, size_t ws_size,
                              hipStream_t stream) {
    const float* X  = (const float*)d_in[0];
    const int*   ei = (const int*)d_in[1];
    const float* W  = (const float*)d_in[2];
    const float* b  = (const float*)d_in[3];
    float* out = (float*)d_out;
    char* ws = (char*)d_ws;
    const size_t MB = 1u << 20;

    float* At  = (float*)ws;                            // [0, 1M)
    short* Atp = (short*)(ws + 1 * MB);                 // [1M, 1.5M) packed A-frag
    short* Wt2 = (short*)(ws + 1 * MB + 512 * 1024);    // 96 KiB
    short* W0p = (short*)(ws + 1 * MB + 608 * 1024);    // 32 KiB packed W0 B-frag

    k_zero   <<<1024, 256, 0, stream>>>(At);
    k_edges  <<<1, 1024, 0, stream>>>(ei, At);
    k_wt2    <<<192, 256, 0, stream>>>(W, Wt2);
    k_pack_at<<<128, 256, 0, stream>>>(At, Atp);
    k_pack_w0<<<8, 256, 0, stream>>>(W, W0p);

    if (ws_size >= 194 * MB) {
        // Y1T @2M (64M), Y2 @66M (64M, region reused as P1x after k_t), Y2T @130M
        short* Y1T = (short*)(ws + 2 * MB);
        short* Y2  = (short*)(ws + 66 * MB);
        short* Y2T = (short*)(ws + 130 * MB);
        short* P1x = Y2;   // alias: Y2 dead after k_t
        k_y <<<2048, 256, 0, stream>>>(X, Wt2, Y1T, Y2);
        k_t <<<2048, 256, 0, stream>>>(Y2, Y2T);
        k_p1<<<1024, 512, 0, stream>>>(Atp, Y1T, P1x);
        k_f <<<1024, 512, 0, stream>>>(X, Atp, Y2T, W0p, P1x, b, out);
    } else {
        short* X1b = (short*)(ws + 2 * MB);
        short* X2b = (short*)(ws + 66 * MB);
        k_agg_fb  <<<4096, 256, 0, stream>>>(X, At, X1b, X2b);
        k_final_fb<<<2048, 256, 0, stream>>>(X, X1b, X2b, Wt2, b, out);
    }
}

// Round 7
// 509.990 us; speedup vs baseline: 1.3246x; 1.3246x over previous
//
#include <hip/hip_runtime.h>
#include <hip/hip_bf16.h>
#include <stdint.h>

// Sizes (fixed by the problem)
#define NN 512
#define DD 128
#define EE 16384

typedef short bf16x8 __attribute__((ext_vector_type(8)));
typedef short bf16x4 __attribute__((ext_vector_type(4)));
typedef float f32x4  __attribute__((ext_vector_type(4)));
typedef unsigned int u32;

__device__ __forceinline__ short f2bf(float f) {
    union { __hip_bfloat16 h; short s; } u;
    u.h = __float2bfloat16(f);
    return u.s;
}
__device__ __forceinline__ u32 pk2(float a, float b) {
    return (u32)(unsigned short)f2bf(a) | ((u32)(unsigned short)f2bf(b) << 16);
}

// async global->LDS 16B copy. LDS dest = wave-uniform base + lane*16 (linear in
// tid); XOR swizzle is applied on the SOURCE chunk index.
typedef __attribute__((address_space(3))) unsigned int lds_u32;
typedef __attribute__((address_space(1))) const unsigned int glb_u32;
__device__ __forceinline__ void gll16(void* l, const void* g) {
    __builtin_amdgcn_global_load_lds((glb_u32*)g, (lds_u32*)l, 16, 0, 0);
}

// ---------------- tiny prep kernels ----------------

__global__ void k_zero(float* __restrict__ At) {
    At[blockIdx.x * 256 + threadIdx.x] = 0.0f;
}

// Build At[dst][src] += 1.  Robust to int32 or int64 input (for int64 LE every
// odd 32-bit word is 0 since values < 512).
__global__ void k_edges(const int* __restrict__ ei, float* __restrict__ At) {
    __shared__ int flag;
    if (threadIdx.x == 0) flag = 0;
    __syncthreads();
    int any = 0;
    for (int i = threadIdx.x; i < EE; i += blockDim.x) any |= ei[2 * i + 1];
    if (any) atomicOr(&flag, 1);
    __syncthreads();
    const bool is32 = (flag != 0);
    for (int e = threadIdx.x; e < EE; e += blockDim.x) {
        int src, dst;
        if (is32) { src = ei[e];     dst = ei[EE + e]; }
        else      { src = ei[2 * e]; dst = ei[2 * (EE + e)]; }
        atomicAdd(&At[dst * NN + src], 1.0f);
    }
}

// Wt2[s][n][d] = bf16(W[(s*128+d)*128 + n])  (k_y W staging)
__global__ void k_wt2(const float* __restrict__ W, short* __restrict__ Wt2) {
    int t = blockIdx.x * 256 + threadIdx.x;     // t = kk*128 + n, kk = s*128+d
    int kk = t >> 7, n = t & 127;
    int s = kk >> 7, d = kk & 127;
    Wt2[s * 16384 + n * 128 + d] = f2bf(W[t]);
}

// Pack At into MFMA A-fragment tile order: tile T = rt*16 + kt covers rows
// rt*16..+16, cols kt*32..+32; lane l holds At[rt*16 + (l&15)][kt*32 + (l>>4)*8 + e].
__global__ void k_pack_at(const float* __restrict__ At, short* __restrict__ Atp) {
    int t = blockIdx.x * 256 + threadIdx.x;     // 32768 threads
    int T = t >> 6, l = t & 63;
    int row = (T >> 4) * 16 + (l & 15);
    int col = (T & 15) * 32 + (l >> 4) * 8;
    const float* s = &At[row * 512 + col];
    bf16x8 p;
    #pragma unroll
    for (int e = 0; e < 8; ++e) p[e] = f2bf(s[e]);
    *(bf16x8*)&Atp[(size_t)T * 512 + l * 8] = p;
}

// Pack W0 into MFMA B-fragment tiles: T = nt*4 + kt; lane l holds
// W0^T[n = nt*16+(l&15)][d = kt*32+(l>>4)*8+e] = W[d*128+n].  32 KB, L2-hot.
__global__ void k_pack_w0(const float* __restrict__ W, short* __restrict__ W0p) {
    int t = blockIdx.x * 256 + threadIdx.x;     // 2048 threads
    int T = t >> 6, l = t & 63;
    int nt = T >> 2, kt = T & 3;
    int n  = nt * 16 + (l & 15);
    int d0 = kt * 32 + (l >> 4) * 8;
    bf16x8 p;
    #pragma unroll
    for (int e = 0; e < 8; ++e) p[e] = f2bf(W[(d0 + e) * 128 + n]);
    *(bf16x8*)&W0p[(size_t)T * 512 + l * 8] = p;
}

// ---------------- k_y: Y1T / Y2 from one pass over X (round-0, proven) --------
// block b: i = b>>2, j0 = (b&3)*128; rows m = (i, j0+r).
// Y1T[i][n][m] = bf16( sum_d X[i][m][d] W1[d][n] )  -> flat B^T[(i,n)][m]
// Y2 [i][m][n] = bf16( sum_d X[i][m][d] W2[d][n] )  (natural)
__global__ __launch_bounds__(256) void k_y(const float* __restrict__ X,
                                           const short* __restrict__ Wt2,
                                           short* __restrict__ Y1T,
                                           short* __restrict__ Y2) {
    __shared__ __align__(16) short Xs[16384];   // [kb][r][64 swizzled]
    __shared__ __align__(16) short Ws[16384];   // [kb][n][64 swizzled]; epilogue scratch

    const int tid  = threadIdx.x;
    const int lane = tid & 63;
    const int wv   = tid >> 6;
    const int wr   = (wv >> 1) * 64;
    const int wc   = (wv & 1) * 64;
    const int lm   = lane & 15;
    const int lq   = lane >> 4;
    const int i  = blockIdx.x >> 2;
    const int j0 = (blockIdx.x & 3) * 128;

    // stage X tile once: fp32 -> bf16, contiguous 64 KB region, coalesced
    #pragma unroll
    for (int it = 0; it < 16; ++it) {
        int g = tid + it * 256;
        int r = g >> 5, c4 = g & 31;
        float4 v = *(const float4*)&X[i * 65536 + (j0 + r) * 128 + c4 * 4];
        int kb = c4 >> 4, c = c4 & 15, p = c >> 1, h2 = c & 1;
        bf16x4 pc; pc[0] = f2bf(v.x); pc[1] = f2bf(v.y); pc[2] = f2bf(v.z); pc[3] = f2bf(v.w);
        *(bf16x4*)&Xs[kb * 8192 + r * 64 + ((p ^ (r & 7)) * 8 + h2 * 4)] = pc;
    }

    #pragma unroll
    for (int s = 1; s <= 2; ++s) {
        // stage W[s] (both kb halves): dest linear, src chunk XOR-swizzled
        #pragma unroll
        for (int it = 0; it < 8; ++it) {
            int slot = it * 256 + tid;              // = kb*1024 + n*8 + pc
            int kb = slot >> 10, rem = slot & 1023;
            int n = rem >> 3, pc = rem & 7;
            gll16(&Ws[slot * 8],
                  &Wt2[s * 16384 + n * 128 + kb * 64 + ((pc ^ (n & 7)) * 8)]);
        }
        __syncthreads();

        f32x4 acc[4][4] = {};
        #pragma unroll
        for (int kb = 0; kb < 2; ++kb)
            #pragma unroll
            for (int ks = 0; ks < 2; ++ks) {
                bf16x8 af[4], bf[4];
                #pragma unroll
                for (int mf = 0; mf < 4; ++mf) {
                    int R = wr + mf * 16 + lm, Cc = ks * 4 + lq;
                    af[mf] = *(const bf16x8*)&Xs[kb * 8192 + R * 64 + (Cc ^ (R & 7)) * 8];
                }
                #pragma unroll
                for (int nf = 0; nf < 4; ++nf) {
                    int R = wc + nf * 16 + lm, Cc = ks * 4 + lq;
                    bf[nf] = *(const bf16x8*)&Ws[kb * 8192 + R * 64 + (Cc ^ (R & 7)) * 8];
                }
                #pragma unroll
                for (int mf = 0; mf < 4; ++mf)
                    #pragma unroll
                    for (int nf = 0; nf < 4; ++nf)
                        acc[mf][nf] = __builtin_amdgcn_mfma_f32_16x16x32_bf16(
                            af[mf], bf[nf], acc[mf][nf], 0, 0, 0);
            }
        __syncthreads();   // MFMA reads of Ws done -> safe to reuse as scratch

        if (s == 1) {
            // transposed epilogue: T[n][m] u32-pairs, XOR-swizzled, b64 writes
            u32* T = (u32*)Ws;
            #pragma unroll
            for (int mf = 0; mf < 4; ++mf)
                #pragma unroll
                for (int nf = 0; nf < 4; ++nf) {
                    int n = wc + nf * 16 + lm;
                    int jb = wr + mf * 16 + lq * 4;   // multiple of 4
                    int w = jb >> 1;                   // even
                    u32 lo = pk2(acc[mf][nf][0], acc[mf][nf][1]);
                    u32 hi = pk2(acc[mf][nf][2], acc[mf][nf][3]);
                    uint2 val; val.x = lo; val.y = hi;
                    *(uint2*)&T[n * 64 + (w ^ (n & 28))] = val;
                }
            __syncthreads();
            #pragma unroll
            for (int it = 0; it < 8; ++it) {
                int ch = tid & 15, n = (tid >> 4) + it * 16;
                uint4 q = *(const uint4*)&T[n * 64 + ((ch * 4) ^ (n & 28))];
                *(uint4*)&Y1T[i * 65536 + n * 512 + j0 + ch * 8] = q;
            }
            __syncthreads();   // before s=2 W staging overwrites T
        } else {
            // natural epilogue via LDS round-trip -> coalesced 16B stores
            #pragma unroll
            for (int mf = 0; mf < 4; ++mf)
                #pragma unroll
                for (int nf = 0; nf < 4; ++nf)
                    #pragma unroll
                    for (int r = 0; r < 4; ++r)
                        Ws[(wr + mf * 16 + lq * 4 + r) * 128 + wc + nf * 16 + lm]
                            = f2bf(acc[mf][nf][r]);
            __syncthreads();
            #pragma unroll
            for (int it = 0; it < 8; ++it) {
                int q = tid + it * 256;
                int row = q >> 4, oc = (q & 15) * 8;
                *(bf16x8*)&Y2[i * 65536 + (j0 + row) * 128 + oc]
                    = *(const bf16x8*)&Ws[row * 128 + oc];
            }
        }
    }
}

// ---------------- k_t: bf16 transpose Y2[k][j][n] -> Y2T[j][n][k] ----------------
__global__ __launch_bounds__(256) void k_t(const short* __restrict__ Y2,
                                           short* __restrict__ Y2T) {
    __shared__ __align__(16) u32 U[128 * 64];   // U[n][a]: (k=2a, 2a+1) packed
    const int tid = threadIdx.x;
    const int bid = (blockIdx.x & 7) * 256 + (blockIdx.x >> 3);   // 2048 % 8 == 0
    const int j  = bid >> 2;
    const int k0 = (bid & 3) * 128;

    const int c8 = tid & 15;         // 8-n chunk
    const int a0 = tid >> 4;         // pair index base
    #pragma unroll
    for (int it = 0; it < 4; ++it) {
        int a = a0 + it * 16;        // 0..63
        const short* r0 = &Y2[(size_t)(k0 + 2 * a) * 65536 + j * 128 + c8 * 8];
        bf16x8 A0 = *(const bf16x8*)r0;
        bf16x8 A1 = *(const bf16x8*)(r0 + 65536);
        #pragma unroll
        for (int cc = 0; cc < 8; ++cc) {
            int n = c8 * 8 + cc;
            U[n * 64 + (a ^ (n & 28))] =
                (u32)(unsigned short)A0[cc] | ((u32)(unsigned short)A1[cc] << 16);
        }
    }
    __syncthreads();
    const int ch = tid & 15;
    const int n0 = tid >> 4;
    #pragma unroll
    for (int it = 0; it < 8; ++it) {
        int n = n0 + it * 16;
        uint4 q = *(const uint4*)&U[n * 64 + ((ch * 4) ^ (n & 28))];
        *(uint4*)&Y2T[j * 65536 + n * 512 + k0 + ch * 8] = q;
    }
}

// ---------------- k_p1: flat GEMM P1x[j][(i,n)] = At @ Y1T^T ----------------
// Y1T is already flat B^T[(i*128+n)][m].  Tile 128(j) x 256(N), 512 thr,
// 8 waves 2x4, 64 KB LDS dbuf, Atp-direct hoisted A-frags, XCD swizzle.
// launch_bounds(512,2): 256-reg cap (per-wave live ~100) -> no spill; residency
// LDS-limited at 2 blocks/CU.
__global__ __launch_bounds__(512, 2) void k_p1(const short* __restrict__ Atp,
                                               const short* __restrict__ Y1T,
                                               short* __restrict__ P1x) {
    __shared__ __align__(16) short sm[32768];   // 64 KB: two 32 KB buffers

    const int tid  = threadIdx.x;
    const int lane = tid & 63;
    const int wv   = tid >> 6;
    const int wrM  = (wv >> 2) * 64;     // j within tile
    const int wcN  = (wv & 3) * 64;      // N within tile
    const int lm   = lane & 15;
    const int lq   = lane >> 4;
    const int lin = (blockIdx.x & 7) * 128 + (blockIdx.x >> 3);   // 1024 % 8 == 0
    const int j0 = (lin & 3) * 128;
    const int N0 = (lin >> 2) * 256;
    const int jt0 = (j0 >> 4) + (wrM >> 4);

    f32x4 acc[4][4] = {};

    // prologue: stage kb=0 into buffer 0 (32 KB: 256 N-rows x 64 k)
    #pragma unroll
    for (int it = 0; it < 4; ++it) {
        int slot = it * 512 + tid;
        int r = slot >> 3, p = slot & 7;
        gll16(&sm[slot * 8], &Y1T[(size_t)(N0 + r) * 512 + ((p ^ (r & 7)) * 8)]);
    }
    __syncthreads();

    for (int kb = 0; kb < 8; ++kb) {
        short* cur = (kb & 1) ? sm + 16384 : sm;
        short* nxt = (kb & 1) ? sm : sm + 16384;

        // A-frags FIRST (oldest vmcnt entries)
        bf16x8 afr[2][4];
        #pragma unroll
        for (int ks = 0; ks < 2; ++ks)
            #pragma unroll
            for (int mf = 0; mf < 4; ++mf)
                afr[ks][mf] = *(const bf16x8*)&Atp[(size_t)((jt0 + mf) * 16 + kb * 2 + ks) * 512 + lane * 8];
        __builtin_amdgcn_sched_barrier(0);

        if (kb < 7) {
            const int k0n = (kb + 1) * 64;
            #pragma unroll
            for (int it = 0; it < 4; ++it) {
                int slot = it * 512 + tid;
                int r = slot >> 3, p = slot & 7;
                gll16(&nxt[slot * 8], &Y1T[(size_t)(N0 + r) * 512 + k0n + ((p ^ (r & 7)) * 8)]);
            }
        }

        #pragma unroll
        for (int ks = 0; ks < 2; ++ks) {
            bf16x8 bf[4];
            #pragma unroll
            for (int nf = 0; nf < 4; ++nf) {
                int R = wcN + nf * 16 + lm, Cc = ks * 4 + lq;
                bf[nf] = *(const bf16x8*)&cur[R * 64 + (Cc ^ (R & 7)) * 8];
            }
            #pragma unroll
            for (int mf = 0; mf < 4; ++mf)
                #pragma unroll
                for (int nf = 0; nf < 4; ++nf)
                    acc[mf][nf] = __builtin_amdgcn_mfma_f32_16x16x32_bf16(
                        afr[ks][mf], bf[nf], acc[mf][nf], 0, 0, 0);
        }
        __syncthreads();
    }

    // epilogue: 128 j-rows x 256 N bf16 via full-LDS roundtrip
    #pragma unroll
    for (int mf = 0; mf < 4; ++mf)
        #pragma unroll
        for (int nf = 0; nf < 4; ++nf)
            #pragma unroll
            for (int rr = 0; rr < 4; ++rr)
                sm[(wrM + mf * 16 + lq * 4 + rr) * 256 + wcN + nf * 16 + lm]
                    = f2bf(acc[mf][nf][rr]);
    __syncthreads();
    #pragma unroll
    for (int it = 0; it < 8; ++it) {
        int q = tid + it * 512;
        int row = q >> 5, oc = (q & 31) * 8;
        *(bf16x8*)&P1x[(size_t)(j0 + row) * 65536 + N0 + oc]
            = *(const bf16x8*)&sm[row * 256 + oc];
    }
}

// ---------------- k_f: out[i][(j,n)] = At@Y2T^T + X@W0 + P1x + b ----------------
// Y2T is flat B^T[(j*128+n)][k]; out is naturally N-flat. Tile 128(i) x 256(N).
__global__ __launch_bounds__(512, 2) void k_f(const float* __restrict__ X,
                                              const short* __restrict__ Atp,
                                              const short* __restrict__ Y2T,
                                              const short* __restrict__ W0p,
                                              const short* __restrict__ P1x,
                                              const float* __restrict__ bias,
                                              float* __restrict__ out) {
    __shared__ __align__(16) short sm[32768];   // 64 KB

    const int tid  = threadIdx.x;
    const int lane = tid & 63;
    const int wv   = tid >> 6;
    const int wrM  = (wv >> 2) * 64;     // i within tile
    const int wcN  = (wv & 3) * 64;      // N within tile
    const int lm   = lane & 15;
    const int lq   = lane >> 4;
    const int lin = (blockIdx.x & 7) * 128 + (blockIdx.x >> 3);
    const int i0  = (lin & 3) * 128;
    const int N0  = (lin >> 2) * 256;
    const int jb0 = N0 >> 7;             // base j of the pair

    f32x4 acc[4][4] = {};

    // ---- phase 1: X@W0 over the j-pair; A = X[i0..+128][jb0..jb0+1][d] ----
    // stage 128 rows x 256 floats (1 KB contiguous per row) -> bf16 swizzled
    #pragma unroll
    for (int it = 0; it < 16; ++it) {
        int g = tid + it * 512;
        int r = g >> 6, c4 = g & 63;
        float4 v = *(const float4*)&X[(size_t)(i0 + r) * 65536 + jb0 * 128 + c4 * 4];
        int jp = c4 >> 5, cc = c4 & 31;
        int kb = cc >> 4, c = cc & 15, p = c >> 1, h2 = c & 1;
        bf16x4 pc; pc[0] = f2bf(v.x); pc[1] = f2bf(v.y); pc[2] = f2bf(v.z); pc[3] = f2bf(v.w);
        *(bf16x4*)&sm[jp * 16384 + kb * 8192 + r * 64 + ((p ^ (r & 7)) * 8 + h2 * 4)] = pc;
    }
    __syncthreads();
    {
        const int jpw = (wv & 3) >> 1;          // wave's j' within pair
        const int ntb = (wv & 1) * 4;           // W0p n-tile base
        #pragma unroll
        for (int kb = 0; kb < 2; ++kb)
            #pragma unroll
            for (int ks = 0; ks < 2; ++ks) {
                int kt = kb * 2 + ks, Cc = ks * 4 + lq;
                bf16x8 af[4], bf[4];
                #pragma unroll
                for (int mf = 0; mf < 4; ++mf) {
                    int R = wrM + mf * 16 + lm;
                    af[mf] = *(const bf16x8*)&sm[jpw * 16384 + kb * 8192 + R * 64 + ((Cc ^ (R & 7)) * 8)];
                }
                #pragma unroll
                for (int nf = 0; nf < 4; ++nf)
                    bf[nf] = *(const bf16x8*)&W0p[(size_t)((ntb + nf) * 4 + kt) * 512 + lane * 8];
                #pragma unroll
                for (int mf = 0; mf < 4; ++mf)
                    #pragma unroll
                    for (int nf = 0; nf < 4; ++nf)
                        acc[mf][nf] = __builtin_amdgcn_mfma_f32_16x16x32_bf16(
                            af[mf], bf[nf], acc[mf][nf], 0, 0, 0);
            }
    }
    __syncthreads();

    // ---- phase 2: At@Y2T^T, K=512, dbuf + hoisted Atp A-frags ----
    const int it0 = (i0 >> 4) + (wrM >> 4);
    #pragma unroll
    for (int it = 0; it < 4; ++it) {
        int slot = it * 512 + tid;
        int r = slot >> 3, p = slot & 7;
        gll16(&sm[slot * 8], &Y2T[(size_t)(N0 + r) * 512 + ((p ^ (r & 7)) * 8)]);
    }
    __syncthreads();

    for (int kb = 0; kb < 8; ++kb) {
        short* cur = (kb & 1) ? sm + 16384 : sm;
        short* nxt = (kb & 1) ? sm : sm + 16384;

        bf16x8 afr[2][4];
        #pragma unroll
        for (int ks = 0; ks < 2; ++ks)
            #pragma unroll
            for (int mf = 0; mf < 4; ++mf)
                afr[ks][mf] = *(const bf16x8*)&Atp[(size_t)((it0 + mf) * 16 + kb * 2 + ks) * 512 + lane * 8];
        __builtin_amdgcn_sched_barrier(0);

        if (kb < 7) {
            const int k0n = (kb + 1) * 64;
            #pragma unroll
            for (int it = 0; it < 4; ++it) {
                int slot = it * 512 + tid;
                int r = slot >> 3, p = slot & 7;
                gll16(&nxt[slot * 8], &Y2T[(size_t)(N0 + r) * 512 + k0n + ((p ^ (r & 7)) * 8)]);
            }
        }

        #pragma unroll
        for (int ks = 0; ks < 2; ++ks) {
            bf16x8 bf[4];
            #pragma unroll
            for (int nf = 0; nf < 4; ++nf) {
                int R = wcN + nf * 16 + lm, Cc = ks * 4 + lq;
                bf[nf] = *(const bf16x8*)&cur[R * 64 + (Cc ^ (R & 7)) * 8];
            }
            #pragma unroll
            for (int mf = 0; mf < 4; ++mf)
                #pragma unroll
                for (int nf = 0; nf < 4; ++nf)
                    acc[mf][nf] = __builtin_amdgcn_mfma_f32_16x16x32_bf16(
                        afr[ks][mf], bf[nf], acc[mf][nf], 0, 0, 0);
        }
        __syncthreads();
    }

    // ---- fused epilogue: + P1x + bias -> fp32 out (N-flat contiguous) ----
    #pragma unroll
    for (int mf = 0; mf < 4; ++mf)
        #pragma unroll
        for (int nf = 0; nf < 4; ++nf)
            #pragma unroll
            for (int rr = 0; rr < 4; ++rr)
                sm[(wrM + mf * 16 + lq * 4 + rr) * 256 + wcN + nf * 16 + lm]
                    = f2bf(acc[mf][nf][rr]);
    __syncthreads();
    #pragma unroll
    for (int it = 0; it < 8; ++it) {
        int q = tid + it * 512;
        int row = q >> 5, oc = (q & 31) * 8;
        int jp2 = oc >> 7, n = oc & 127;
        bf16x8 vs = *(const bf16x8*)&sm[row * 256 + oc];
        bf16x8 vpl = *(const bf16x8*)&P1x[(size_t)(jb0 + jp2) * 65536 + (i0 + row) * 128 + n];
        float4 b0 = *(const float4*)&bias[n];
        float4 b1 = *(const float4*)&bias[n + 4];
        union { short s; __hip_bfloat16 h; } cs, cp;
        float o[8];
        #pragma unroll
        for (int e = 0; e < 8; ++e) {
            cs.s = vs[e]; cp.s = vpl[e];
            o[e] = __bfloat162float(cs.h) + __bfloat162float(cp.h);
        }
        o[0] += b0.x; o[1] += b0.y; o[2] += b0.z; o[3] += b0.w;
        o[4] += b1.x; o[5] += b1.y; o[6] += b1.z; o[7] += b1.w;
        float* op = &out[(size_t)(i0 + row) * 65536 + N0 + oc];
        float4 w0; w0.x = o[0]; w0.y = o[1]; w0.z = o[2]; w0.w = o[3];
        float4 w1; w1.x = o[4]; w1.y = o[5]; w1.z = o[6]; w1.w = o[7];
        *(float4*)op = w0;
        *(float4*)(op + 4) = w1;
    }
}

// ================= fallback path (round-1, proven, 130 MiB ws) =================

__global__ __launch_bounds__(256) void k_agg_fb(const float* __restrict__ X,
                                                const float* __restrict__ At,
                                                short* __restrict__ X1b,
                                                short* __restrict__ X2b) {
    __shared__ short As[128 * 72];
    __shared__ short Bs[128 * 72];
    const int tid  = threadIdx.x;
    const int lane = tid & 63;
    const int wv   = tid >> 6;
    const int wr   = (wv >> 1) * 64;
    const int wc   = (wv & 1) * 64;
    const int lm   = lane & 15;
    const int lq   = lane >> 4;
    int a0, Bbase, Bks, Cbase, Crs;
    short* Cp;
    const int bidx = blockIdx.x;
    if (bidx < 2048) {
        int i = bidx >> 2, jt = bidx & 3;
        a0 = jt * 128; Bbase = i * 65536; Bks = 128;
        Cbase = i * 65536 + jt * 16384; Crs = 128; Cp = X1b;
    } else {
        int bb = bidx - 2048;
        int j = bb >> 2, it = bb & 3;
        a0 = it * 128; Bbase = j * 128; Bks = 65536;
        Cbase = it * 8388608 + j * 128; Crs = 65536; Cp = X2b;
    }
    f32x4 acc[4][4] = {};
    const int d  = tid & 127;
    const int kh = tid >> 7;
    for (int kb = 0; kb < 8; ++kb) {
        const int k0 = kb * 64;
        #pragma unroll
        for (int it8 = 0; it8 < 8; ++it8) {
            int g = tid + it8 * 256;
            int r = g >> 4, kq = (g & 15) * 4;
            float4 v = *(const float4*)&At[(a0 + r) * 512 + k0 + kq];
            bf16x4 p; p[0] = f2bf(v.x); p[1] = f2bf(v.y); p[2] = f2bf(v.z); p[3] = f2bf(v.w);
            *(bf16x4*)&As[r * 72 + kq] = p;
        }
        #pragma unroll
        for (int gi = 0; gi < 4; ++gi) {
            int kg = kh * 4 + gi;
            bf16x8 p;
            #pragma unroll
            for (int jj = 0; jj < 8; ++jj)
                p[jj] = f2bf(X[Bbase + (k0 + kg * 8 + jj) * Bks + d]);
            *(bf16x8*)&Bs[d * 72 + kg * 8] = p;
        }
        __syncthreads();
        #pragma unroll
        for (int ks = 0; ks < 2; ++ks) {
            bf16x8 af[4], bfr[4];
            #pragma unroll
            for (int mf = 0; mf < 4; ++mf)
                af[mf] = *(const bf16x8*)&As[(wr + mf * 16 + lm) * 72 + ks * 32 + lq * 8];
            #pragma unroll
            for (int nf = 0; nf < 4; ++nf)
                bfr[nf] = *(const bf16x8*)&Bs[(wc + nf * 16 + lm) * 72 + ks * 32 + lq * 8];
            #pragma unroll
            for (int mf = 0; mf < 4; ++mf)
                #pragma unroll
                for (int nf = 0; nf < 4; ++nf)
                    acc[mf][nf] = __builtin_amdgcn_mfma_f32_16x16x32_bf16(
                        af[mf], bfr[nf], acc[mf][nf], 0, 0, 0);
        }
        __syncthreads();
    }
    #pragma unroll
    for (int mf = 0; mf < 4; ++mf)
        #pragma unroll
        for (int nf = 0; nf < 4; ++nf)
            #pragma unroll
            for (int r = 0; r < 4; ++r) {
                int row = wr + mf * 16 + lq * 4 + r;
                int col = wc + nf * 16 + lm;
                Cp[Cbase + row * Crs + col] = f2bf(acc[mf][nf][r]);
            }
}

__global__ __launch_bounds__(256) void k_final_fb(const float* __restrict__ X,
                                                  const short* __restrict__ X1b,
                                                  const short* __restrict__ X2b,
                                                  const short* __restrict__ Wt2,
                                                  const float* __restrict__ bias,
                                                  float* __restrict__ out) {
    __shared__ short As[128 * 72];
    __shared__ short Ws[128 * 72];
    const int tid  = threadIdx.x;
    const int lane = tid & 63;
    const int wv   = tid >> 6;
    const int wr   = (wv >> 1) * 64;
    const int wc   = (wv & 1) * 64;
    const int lm   = lane & 15;
    const int lq   = lane >> 4;
    const int m0   = blockIdx.x * 128;
    f32x4 acc[4][4] = {};
    for (int ph = 0; ph < 6; ++ph) {
        const int s = ph >> 1, h = ph & 1;
        if (s == 0) {
            #pragma unroll
            for (int it8 = 0; it8 < 8; ++it8) {
                int g = tid + it8 * 256;
                int r = g >> 4, kq = (g & 15) * 4;
                float4 v = *(const float4*)&X[(m0 + r) * 128 + h * 64 + kq];
                bf16x4 p; p[0] = f2bf(v.x); p[1] = f2bf(v.y); p[2] = f2bf(v.z); p[3] = f2bf(v.w);
                *(bf16x4*)&As[r * 72 + kq] = p;
            }
        } else {
            const short* src = (s == 1) ? X1b : X2b;
            #pragma unroll
            for (int it4 = 0; it4 < 4; ++it4) {
                int g = tid + it4 * 256;
                int r = g >> 3, ko = (g & 7) * 8;
                *(bf16x8*)&As[r * 72 + ko] =
                    *(const bf16x8*)&src[(m0 + r) * 128 + h * 64 + ko];
            }
        }
        #pragma unroll
        for (int it4 = 0; it4 < 4; ++it4) {
            int g = tid + it4 * 256;
            int n = g >> 3, ko = (g & 7) * 8;
            *(bf16x8*)&Ws[n * 72 + ko] =
                *(const bf16x8*)&Wt2[s * 16384 + n * 128 + h * 64 + ko];
        }
        __syncthreads();
        #pragma unroll
        for (int ks = 0; ks < 2; ++ks) {
            bf16x8 af[4], bfr[4];
            #pragma unroll
            for (int mf = 0; mf < 4; ++mf)
                af[mf] = *(const bf16x8*)&As[(wr + mf * 16 + lm) * 72 + ks * 32 + lq * 8];
            #pragma unroll
            for (int nf = 0; nf < 4; ++nf)
                bfr[nf] = *(const bf16x8*)&Ws[(wc + nf * 16 + lm) * 72 + ks * 32 + lq * 8];
            #pragma unroll
            for (int mf = 0; mf < 4; ++mf)
                #pragma unroll
                for (int nf = 0; nf < 4; ++nf)
                    acc[mf][nf] = __builtin_amdgcn_mfma_f32_16x16x32_bf16(
                        af[mf], bfr[nf], acc[mf][nf], 0, 0, 0);
        }
        __syncthreads();
    }
    #pragma unroll
    for (int nf = 0; nf < 4; ++nf) {
        float bv = bias[wc + nf * 16 + lm];
        #pragma unroll
        for (int mf = 0; mf < 4; ++mf)
            #pragma unroll
            for (int r = 0; r < 4; ++r) {
                int row = m0 + wr + mf * 16 + lq * 4 + r;
                int col = wc + nf * 16 + lm;
                out[row * 128 + col] = acc[mf][nf][r] + bv;
            }
    }
}

extern "C" void kernel_launch(void* const* d_in, const int* in_sizes, int n_in,
                              void* d_out, int out_size, void* d_ws, size_t ws_size,
                              hipStream_t stream) {
    const float* X  = (const float*)d_in[0];
    const int*   ei = (const int*)d_in[1];
    const float* W  = (const float*)d_in[2];
    const float* b  = (const float*)d_in[3];
    float* out = (float*)d_out;
    char* ws = (char*)d_ws;
    const size_t MB = 1u << 20;

    float* At  = (float*)ws;                            // [0, 1M)
    short* Atp = (short*)(ws + 1 * MB);                 // [1M, 1.5M) packed A-frag
    short* Wt2 = (short*)(ws + 1 * MB + 512 * 1024);    // 96 KiB
    short* W0p = (short*)(ws + 1 * MB + 608 * 1024);    // 32 KiB packed W0 B-frag

    k_zero   <<<1024, 256, 0, stream>>>(At);
    k_edges  <<<1, 1024, 0, stream>>>(ei, At);
    k_wt2    <<<192, 256, 0, stream>>>(W, Wt2);
    k_pack_at<<<128, 256, 0, stream>>>(At, Atp);
    k_pack_w0<<<8, 256, 0, stream>>>(W, W0p);

    if (ws_size >= 194 * MB) {
        // Y1T @2M (64M), Y2 @66M (64M, region reused as P1x after k_t), Y2T @130M
        short* Y1T = (short*)(ws + 2 * MB);
        short* Y2  = (short*)(ws + 66 * MB);
        short* Y2T = (short*)(ws + 130 * MB);
        short* P1x = Y2;   // alias: Y2 dead after k_t
        k_y <<<2048, 256, 0, stream>>>(X, Wt2, Y1T, Y2);
        k_t <<<2048, 256, 0, stream>>>(Y2, Y2T);
        k_p1<<<1024, 512, 0, stream>>>(Atp, Y1T, P1x);
        k_f <<<1024, 512, 0, stream>>>(X, Atp, Y2T, W0p, P1x, b, out);
    } else {
        short* X1b = (short*)(ws + 2 * MB);
        short* X2b = (short*)(ws + 66 * MB);
        k_agg_fb  <<<4096, 256, 0, stream>>>(X, At, X1b, X2b);
        k_final_fb<<<2048, 256, 0, stream>>>(X, X1b, X2b, Wt2, b, out);
    }
}